// Round 9
// baseline (492.015 us; speedup 1.0000x reference)
//
#include <hip/hip_runtime.h>
#include <stdint.h>

#define LOG_B 17
#define NB (1u << LOG_B)
#define FINE_NODES 1024
#define NBKT 512             // fine buckets of 1024 nodes; 489 used for N=500k
#define CSH 10               // dst >> 10 -> bucket
#define EPB 16384
#define ITERS (EPB / 4 / 256)   // 16 full-unroll iterations in fast path

typedef unsigned long long ull;

__host__ __device__ constexpr uint32_t cmix(uint32_t v, uint32_t c1, uint32_t c2) {
    v = (v ^ (v >> 16)) * c1;
    v = (v ^ (v >> 13)) * c2;
    return v ^ (v >> 16);
}

__device__ __forceinline__ uint32_t mixh(uint32_t v, uint32_t c1, uint32_t c2) {
    v = (v ^ (v >> 16)) * c1;
    v = (v ^ (v >> 13)) * c2;
    return v ^ (v >> 16);
}

struct Luts { uint32_t ha[64]; uint32_t hb[64]; };
constexpr Luts make_luts() {
    Luts l{};
    for (uint32_t i = 0; i < 64; i++) {
        l.ha[i] = cmix(i, 0x045D9F3Bu, 0x045D9F3Bu);
        l.hb[i] = cmix(i, 0x9E3779B1u, 0x85EBCA77u);
    }
    return l;
}
__constant__ Luts LUT = make_luts();

// ---- P0: pack labels into u8 ----
__global__ __launch_bounds__(256) void k_pre(const int4* __restrict__ x4,
                                             uchar4* __restrict__ xc4, int n4) {
    int i = blockIdx.x * 256 + threadIdx.x;
    if (i >= n4) return;
    int4 v = x4[i];
    xc4[i] = make_uchar4((uint8_t)v.x, (uint8_t)v.y, (uint8_t)v.z, (uint8_t)v.w);
}

// ---- P1: bin edges (byte-identical to the proven 152 us R4 version) ----
__global__ __launch_bounds__(256, 4) void k_bin(const int* __restrict__ row, const int* __restrict__ col,
                                                const uint8_t* __restrict__ xc, uint16_t* __restrict__ bins,
                                                uint32_t* __restrict__ cursor, int E, int cap) {
    __shared__ uint16_t stage[EPB];       // 32 KB
    __shared__ uint32_t hist[NBKT];       // 2 KB; post-scan: start<<16 | cursor
    __shared__ uint16_t gb16[NBKT];       // 1 KB
    __shared__ uint32_t wsum[4];
    int t = threadIdx.x;
    int lane = t & 63, wid = t >> 6;
    int base = blockIdx.x * EPB;
    int nend = min(E - base, EPB);
    for (int b = t; b < NBKT; b += 256) hist[b] = 0;
    __syncthreads();

    const int4* col4 = (const int4*)(col + base);
    const int4* row4 = (const int4*)(row + base);

    bool fast = (nend == EPB);
    uint32_t rec[ITERS * 4];

    if (fast) {
#pragma unroll
        for (int it = 0; it < ITERS; ++it) {
            int k = t + it * 256;
            int4 c = col4[k];
            int4 r = row4[k];
            atomicAdd(&hist[(uint32_t)c.x >> CSH], 1u);
            atomicAdd(&hist[(uint32_t)c.y >> CSH], 1u);
            atomicAdd(&hist[(uint32_t)c.z >> CSH], 1u);
            atomicAdd(&hist[(uint32_t)c.w >> CSH], 1u);
            rec[it * 4 + 0] = ((uint32_t)c.x << 6) | (uint32_t)xc[r.x];
            rec[it * 4 + 1] = ((uint32_t)c.y << 6) | (uint32_t)xc[r.y];
            rec[it * 4 + 2] = ((uint32_t)c.z << 6) | (uint32_t)xc[r.z];
            rec[it * 4 + 3] = ((uint32_t)c.w << 6) | (uint32_t)xc[r.w];
        }
    } else {
        int n4 = nend >> 2;
        for (int k = t; k < n4; k += 256) {
            int4 c = col4[k];
            atomicAdd(&hist[(uint32_t)c.x >> CSH], 1u);
            atomicAdd(&hist[(uint32_t)c.y >> CSH], 1u);
            atomicAdd(&hist[(uint32_t)c.z >> CSH], 1u);
            atomicAdd(&hist[(uint32_t)c.w >> CSH], 1u);
        }
        for (int k = (n4 << 2) + t; k < nend; k += 256)
            atomicAdd(&hist[(uint32_t)col[base + k] >> CSH], 1u);
    }
    __syncthreads();

    int b0 = 2 * t;
    uint32_t h0 = hist[b0], h1 = hist[b0 + 1];
    uint32_t s = h0 + h1;
    uint32_t inc = s;
    for (int off = 1; off < 64; off <<= 1) {
        uint32_t nv = __shfl_up(inc, (unsigned)off, 64);
        if (lane >= off) inc += nv;
    }
    if (lane == 63) wsum[wid] = inc;
    __syncthreads();
    uint32_t woff = 0;
    for (int w = 0; w < wid; w++) woff += wsum[w];
    uint32_t e0 = woff + inc - s;
    uint32_t g0 = h0 ? atomicAdd(&cursor[b0], h0) : 0u;
    uint32_t g1 = h1 ? atomicAdd(&cursor[b0 + 1], h1) : 0u;
    gb16[b0] = (uint16_t)g0;
    gb16[b0 + 1] = (uint16_t)g1;
    hist[b0] = e0 << 16;
    hist[b0 + 1] = (e0 + h0) << 16;
    __syncthreads();

    if (fast) {
#pragma unroll
        for (int it = 0; it < ITERS * 4; ++it) {
            uint32_t rv = rec[it];
            uint32_t b = rv >> 16;
            uint32_t o = atomicAdd(&hist[b], 1u);
            stage[(o >> 16) + (o & 0xFFFFu)] = (uint16_t)rv;
        }
    } else {
        int n4 = nend >> 2;
        for (int k = t; k < n4; k += 256) {
            int4 c = col4[k];
            int4 r = row4[k];
            {
                uint32_t d = (uint32_t)c.x, b = d >> CSH;
                uint32_t o = atomicAdd(&hist[b], 1u);
                stage[(o >> 16) + (o & 0xFFFFu)] = (uint16_t)(((d & 1023u) << 6) | (uint32_t)xc[r.x]);
            }
            {
                uint32_t d = (uint32_t)c.y, b = d >> CSH;
                uint32_t o = atomicAdd(&hist[b], 1u);
                stage[(o >> 16) + (o & 0xFFFFu)] = (uint16_t)(((d & 1023u) << 6) | (uint32_t)xc[r.y]);
            }
            {
                uint32_t d = (uint32_t)c.z, b = d >> CSH;
                uint32_t o = atomicAdd(&hist[b], 1u);
                stage[(o >> 16) + (o & 0xFFFFu)] = (uint16_t)(((d & 1023u) << 6) | (uint32_t)xc[r.z]);
            }
            {
                uint32_t d = (uint32_t)c.w, b = d >> CSH;
                uint32_t o = atomicAdd(&hist[b], 1u);
                stage[(o >> 16) + (o & 0xFFFFu)] = (uint16_t)(((d & 1023u) << 6) | (uint32_t)xc[r.w]);
            }
        }
        for (int k = (n4 << 2) + t; k < nend; k += 256) {
            int i = base + k;
            uint32_t d = (uint32_t)col[i], b = d >> CSH;
            uint32_t o = atomicAdd(&hist[b], 1u);
            stage[(o >> 16) + (o & 0xFFFFu)] = (uint16_t)(((d & 1023u) << 6) | (uint32_t)xc[row[i]]);
        }
    }
    __syncthreads();

    int sub = lane >> 4, l16 = lane & 15;
    for (int b = wid * 4 + sub; b < NBKT; b += 16) {
        uint32_t hv = hist[b];
        uint32_t cnt = hv & 0xFFFFu;
        if (!cnt) continue;
        uint32_t s0 = hv >> 16;
        uint16_t* dst = bins + (size_t)b * (uint32_t)cap + gb16[b];
        for (uint32_t off = l16; off < cnt; off += 16)
            dst[off] = stage[s0 + off];
    }
}

// ---- P2: direct per-node sum accumulation (byte-identical to R4) ----
__global__ __launch_bounds__(1024) void k_accsig(const uint16_t* __restrict__ bins,
                                                 const uint32_t* __restrict__ cursor,
                                                 const uint8_t* __restrict__ xc,
                                                 ull* __restrict__ sigs,
                                                 uint32_t* __restrict__ bcnt, int N, int cap) {
    __shared__ uint32_t sA[FINE_NODES];   // 4 KB
    __shared__ uint32_t sB[FINE_NODES];   // 4 KB
    __shared__ uint32_t lA[64], lB[64];
    int t = threadIdx.x;
    int b = blockIdx.x;
    sA[t] = 0;
    sB[t] = 0;
    if (t < 64) { lA[t] = LUT.ha[t]; lB[t] = LUT.hb[t]; }
    __syncthreads();

    uint32_t m = cursor[b];
    const uint16_t* mybins = bins + (size_t)b * (uint32_t)cap;
    const uint2* p16v = (const uint2*)mybins;
    uint32_t m4 = m >> 2;
    for (uint32_t k = t; k < m4; k += 1024) {
        uint2 rv = p16v[k];
        {
            uint32_t rec = rv.x & 0xFFFFu, n = rec >> 6, c = rec & 63u;
            atomicAdd(&sA[n], lA[c]);
            atomicAdd(&sB[n], lB[c]);
        }
        {
            uint32_t rec = rv.x >> 16, n = rec >> 6, c = rec & 63u;
            atomicAdd(&sA[n], lA[c]);
            atomicAdd(&sB[n], lB[c]);
        }
        {
            uint32_t rec = rv.y & 0xFFFFu, n = rec >> 6, c = rec & 63u;
            atomicAdd(&sA[n], lA[c]);
            atomicAdd(&sB[n], lB[c]);
        }
        {
            uint32_t rec = rv.y >> 16, n = rec >> 6, c = rec & 63u;
            atomicAdd(&sA[n], lA[c]);
            atomicAdd(&sB[n], lB[c]);
        }
    }
    for (uint32_t k = (m4 << 2) + t; k < m; k += 1024) {
        uint32_t rec = mybins[k], n = rec >> 6, c = rec & 63u;
        atomicAdd(&sA[n], lA[c]);
        atomicAdd(&sB[n], lB[c]);
    }
    __syncthreads();

    int g = b * FINE_NODES + t;
    if (g < N) {
        uint32_t xv = (uint32_t)xc[g];
        uint32_t ha = lA[xv];
        uint32_t hb = lB[xv];
        uint32_t sa = mixh(ha * 0x27D4EB2Fu + sA[t], 0xC2B2AE3Du, 0x165667B1u);
        uint32_t sb = mixh(hb * 0x61C88647u + sB[t], 0x045D9F3Bu, 0x27D4EB2Fu);
        ull key = ((ull)sa << 32) | (ull)sb;
        sigs[g] = key;
        atomicAdd(&bcnt[(uint32_t)(key >> (64 - LOG_B))], 1u);
    }
}

// ---- decoupled-lookback prefix over block aggregates (wave 0 only).
// Proven correct on HW in round 7. agg[i]: status<<32 | value;
// 0=invalid, 1=aggregate, 2=inclusive. ----
__device__ __forceinline__ uint32_t lb_prefix(ull* agg, int bid, int lane) {
    uint32_t prefix = 0;
    int base = bid - 1;
    for (;;) {
        int idx = base - lane;
        ull v;
        if (idx >= 0) {
            do {
                v = __hip_atomic_load(&agg[idx], __ATOMIC_ACQUIRE, __HIP_MEMORY_SCOPE_AGENT);
            } while ((v >> 32) == 0ull);
        } else {
            v = (2ull << 32);
        }
        bool incl = (v >> 32) == 2ull;
        ull mask = __ballot(incl);
        int fl = mask ? (__ffsll(mask) - 1) : 64;
        uint32_t contrib = (lane <= fl) ? (uint32_t)v : 0u;
        for (int off = 32; off; off >>= 1) contrib += __shfl_down(contrib, off, 64);
        contrib = __shfl(contrib, 0, 64);
        prefix += contrib;
        if (fl < 64) return prefix;
        base -= 64;
    }
}

// ---- single-launch exclusive scan of NB elems (128 blocks, uint4/thread,
// lookback replaces the 3-kernel scan chain). All 128 blocks co-resident. ----
__global__ __launch_bounds__(256) void k_scanlb(const uint32_t* __restrict__ in,
                                                uint32_t* __restrict__ out,
                                                ull* __restrict__ agg) {
    __shared__ uint32_t wsum[4];
    __shared__ uint32_t sh_pref;
    int t = threadIdx.x;
    int lane = t & 63, wid = t >> 6;
    int bid = blockIdx.x;
    int base = bid * 1024 + 4 * t;
    uint4 v = *(const uint4*)(in + base);
    uint32_t s = v.x + v.y + v.z + v.w;
    uint32_t inc = s;
    for (int off = 1; off < 64; off <<= 1) {
        uint32_t nv = __shfl_up(inc, (unsigned)off, 64);
        if (lane >= off) inc += nv;
    }
    if (lane == 63) wsum[wid] = inc;
    __syncthreads();
    uint32_t woff = 0;
    for (int w = 0; w < wid; w++) woff += wsum[w];
    uint32_t e = woff + inc - s;
    uint32_t tot = wsum[0] + wsum[1] + wsum[2] + wsum[3];
    if (wid == 0) {
        if (t == 0)
            __hip_atomic_store(&agg[bid], (1ull << 32) | (ull)tot,
                               __ATOMIC_RELEASE, __HIP_MEMORY_SCOPE_AGENT);
        uint32_t pref = 0;
        if (bid > 0) pref = lb_prefix(agg, bid, lane);
        if (t == 0) {
            __hip_atomic_store(&agg[bid], (2ull << 32) | (ull)(tot + pref),
                               __ATOMIC_RELEASE, __HIP_MEMORY_SCOPE_AGENT);
            sh_pref = pref;
        }
    }
    __syncthreads();
    uint32_t p = sh_pref;
    uint4 o;
    o.x = e + p; o.y = o.x + v.x; o.z = o.y + v.y; o.w = o.z + v.z;
    *(uint4*)(out + base) = o;
}

// ---- scatter KEYS ONLY into sort buckets (8B/node random, was 12B) ----
__global__ void k_scatter(const ull* __restrict__ sigs,
                          const uint32_t* __restrict__ boff, uint32_t* __restrict__ bcur,
                          ull* __restrict__ skey, int N) {
    int i = blockIdx.x * blockDim.x + threadIdx.x;
    if (i >= N) return;
    ull key = sigs[i];
    uint32_t b = (uint32_t)(key >> (64 - LOG_B));
    uint32_t pos = boff[b] + atomicAdd(&bcur[b], 1u);
    skey[pos] = key;
}

// ---- per-bucket key sort + distinct count + FUSED rank-base via lookback.
// Replaces k_bsort + scan x3. 512 blocks x 256 thr, all co-resident. ----
__global__ __launch_bounds__(256) void k_bsort2(ull* __restrict__ skey,
                                                const uint32_t* __restrict__ boff,
                                                uint32_t* __restrict__ rbase,
                                                ull* __restrict__ agg, int N) {
    __shared__ uint32_t wsum[4];
    __shared__ uint32_t sh_pref;
    int t = threadIdx.x;
    int lane = t & 63, wid = t >> 6;
    int bid = blockIdx.x;
    int b = bid * 256 + t;
    uint32_t s0 = boff[b];
    uint32_t s1 = (b == (int)NB - 1) ? (uint32_t)N : boff[b + 1];
    for (uint32_t i = s0 + 1; i < s1; i++) {
        ull k = skey[i];
        uint32_t j = i;
        while (j > s0 && skey[j - 1] > k) {
            skey[j] = skey[j - 1];
            j--;
        }
        skey[j] = k;
    }
    uint32_t d = 0;
    ull prev = 0ull;
    for (uint32_t i = s0; i < s1; i++) {
        ull k = skey[i];
        if (i == s0 || k != prev) d++;
        prev = k;
    }
    // block exscan of d + lookback for global base
    uint32_t inc = d;
    for (int off = 1; off < 64; off <<= 1) {
        uint32_t nv = __shfl_up(inc, (unsigned)off, 64);
        if (lane >= off) inc += nv;
    }
    if (lane == 63) wsum[wid] = inc;
    __syncthreads();
    uint32_t woff = 0;
    for (int w = 0; w < wid; w++) woff += wsum[w];
    uint32_t dexcl = woff + inc - d;
    uint32_t tot = wsum[0] + wsum[1] + wsum[2] + wsum[3];
    if (wid == 0) {
        if (t == 0)
            __hip_atomic_store(&agg[bid], (1ull << 32) | (ull)tot,
                               __ATOMIC_RELEASE, __HIP_MEMORY_SCOPE_AGENT);
        uint32_t pref = 0;
        if (bid > 0) pref = lb_prefix(agg, bid, lane);
        if (t == 0) {
            __hip_atomic_store(&agg[bid], (2ull << 32) | (ull)(tot + pref),
                               __ATOMIC_RELEASE, __HIP_MEMORY_SCOPE_AGENT);
            sh_pref = pref;
        }
    }
    __syncthreads();
    rbase[b] = sh_pref + dexcl;
}

// ---- final labels: coalesced sigs read, short bucket probe, COALESCED write.
// (replaces random-write k_out + the snode/ldx arrays entirely) ----
__global__ __launch_bounds__(256) void k_out2(const ull* __restrict__ sigs,
                                              const uint32_t* __restrict__ boff,
                                              const ull* __restrict__ skey,
                                              const uint32_t* __restrict__ rbase,
                                              int* __restrict__ out, int N) {
    int i = blockIdx.x * 256 + threadIdx.x;
    if (i >= N) return;
    ull key = sigs[i];
    uint32_t b = (uint32_t)(key >> (64 - LOG_B));
    uint32_t s0 = boff[b];
    uint32_t d = 0;
    ull prev = 0ull;
    uint32_t j = s0;
    for (;;) {
        ull k = skey[j];
        if (j == s0 || k != prev) d++;
        if (k == key) break;
        prev = k;
        j++;
    }
    out[i] = (int)(rbase[b] + d - 1);
}

extern "C" void kernel_launch(void* const* d_in, const int* in_sizes, int n_in,
                              void* d_out, int out_size, void* d_ws, size_t ws_size,
                              hipStream_t stream) {
    const int* x = (const int*)d_in[0];
    const int* ei = (const int*)d_in[1];
    int N = in_sizes[0];
    int E = in_sizes[1] / 2;
    const int* row = ei;
    const int* col = ei + E;

    int nacc = (N + FINE_NODES - 1) / FINE_NODES;        // 489
    int cap = E / NBKT + (E / NBKT) / 16 + 1024;         // mean + margin (<65536)
    cap = (cap + 3) & ~3;

    char* p = (char*)d_ws;
    auto alloc = [&](size_t bytes) -> char* {
        char* r = p;
        p += (bytes + 255) & ~(size_t)255;
        return r;
    };
    // zero-needing region first (single memsetAsync)
    uint32_t* cursor = (uint32_t*)alloc((size_t)NBKT * 4);
    uint32_t* bcnt   = (uint32_t*)alloc((size_t)NB * 4);
    uint32_t* bcur   = (uint32_t*)alloc((size_t)NB * 4);
    ull* aggB = (ull*)alloc((size_t)(NB / 1024) * 8);    // 128 scan blocks
    ull* aggD = (ull*)alloc((size_t)(NB / 256) * 8);     // 512 bsort blocks
    size_t zbytes = (size_t)(p - (char*)d_ws);
    uint8_t* xc = (uint8_t*)alloc((size_t)N);
    ull* sigs = (ull*)alloc((size_t)N * 8);
    uint16_t* bins = (uint16_t*)alloc((size_t)NBKT * cap * 2);
    // post-accsig aliases inside the (then-dead) bins region:
    char* q = (char*)bins;
    auto alias = [&](size_t bytes) -> char* {
        char* r = q;
        q += (bytes + 255) & ~(size_t)255;
        return r;
    };
    ull* skey       = (ull*)alias((size_t)N * 8);
    uint32_t* boff  = (uint32_t*)alias((size_t)NB * 4);
    uint32_t* rbase = (uint32_t*)alias((size_t)NB * 4);

    hipMemsetAsync(d_ws, 0, zbytes, stream);

    int nbN = (N + 255) / 256;
    int nbBin = (E + EPB - 1) / EPB;
    int n4 = N / 4;

    k_pre<<<(n4 + 255) / 256, 256, 0, stream>>>((const int4*)x, (uchar4*)xc, n4);
    k_bin<<<nbBin, 256, 0, stream>>>(row, col, xc, bins, cursor, E, cap);
    k_accsig<<<nacc, 1024, 0, stream>>>(bins, cursor, xc, sigs, bcnt, N, cap);

    k_scanlb<<<NB / 1024, 256, 0, stream>>>(bcnt, boff, aggB);
    k_scatter<<<nbN, 256, 0, stream>>>(sigs, boff, bcur, skey, N);
    k_bsort2<<<NB / 256, 256, 0, stream>>>(skey, boff, rbase, aggD, N);
    k_out2<<<nbN, 256, 0, stream>>>(sigs, boff, skey, rbase, (int*)d_out, N);
}

// Round 10
// 395.968 us; speedup vs baseline: 1.2426x; 1.2426x over previous
//
#include <hip/hip_runtime.h>
#include <stdint.h>

#define LOG_B 17
#define NB (1u << LOG_B)
#define FINE_NODES 1024
#define NBKT 512             // fine buckets of 1024 nodes; 489 used for N=500k
#define CSH 10               // dst >> 10 -> bucket
#define EPB 16384
#define ITERS (EPB / 4 / 256)   // 16 full-unroll iterations in fast path

typedef unsigned long long ull;

__host__ __device__ constexpr uint32_t cmix(uint32_t v, uint32_t c1, uint32_t c2) {
    v = (v ^ (v >> 16)) * c1;
    v = (v ^ (v >> 13)) * c2;
    return v ^ (v >> 16);
}

__device__ __forceinline__ uint32_t mixh(uint32_t v, uint32_t c1, uint32_t c2) {
    v = (v ^ (v >> 16)) * c1;
    v = (v ^ (v >> 13)) * c2;
    return v ^ (v >> 16);
}

struct Luts { uint32_t ha[64]; uint32_t hb[64]; };
constexpr Luts make_luts() {
    Luts l{};
    for (uint32_t i = 0; i < 64; i++) {
        l.ha[i] = cmix(i, 0x045D9F3Bu, 0x045D9F3Bu);
        l.hb[i] = cmix(i, 0x9E3779B1u, 0x85EBCA77u);
    }
    return l;
}
__constant__ Luts LUT = make_luts();

// ---- P0: pack labels into u8 (0.5 MB -> fully L2-resident gather target) ----
__global__ __launch_bounds__(256) void k_pre(const int4* __restrict__ x4,
                                             uchar4* __restrict__ xc4, int n4) {
    int i = blockIdx.x * 256 + threadIdx.x;
    if (i >= n4) return;
    int4 v = x4[i];
    xc4[i] = make_uchar4((uint8_t)v.x, (uint8_t)v.y, (uint8_t)v.z, (uint8_t)v.w);
}

// ---- P1: bin edges (byte-identical to the proven 152 us R4 version) ----
__global__ __launch_bounds__(256, 4) void k_bin(const int* __restrict__ row, const int* __restrict__ col,
                                                const uint8_t* __restrict__ xc, uint16_t* __restrict__ bins,
                                                uint32_t* __restrict__ cursor, int E, int cap) {
    __shared__ uint16_t stage[EPB];       // 32 KB
    __shared__ uint32_t hist[NBKT];       // 2 KB; post-scan: start<<16 | cursor
    __shared__ uint16_t gb16[NBKT];       // 1 KB
    __shared__ uint32_t wsum[4];
    int t = threadIdx.x;
    int lane = t & 63, wid = t >> 6;
    int base = blockIdx.x * EPB;
    int nend = min(E - base, EPB);
    for (int b = t; b < NBKT; b += 256) hist[b] = 0;
    __syncthreads();

    const int4* col4 = (const int4*)(col + base);
    const int4* row4 = (const int4*)(row + base);

    bool fast = (nend == EPB);
    uint32_t rec[ITERS * 4];              // 64 VGPRs, static indexing only

    if (fast) {
#pragma unroll
        for (int it = 0; it < ITERS; ++it) {
            int k = t + it * 256;
            int4 c = col4[k];
            int4 r = row4[k];
            atomicAdd(&hist[(uint32_t)c.x >> CSH], 1u);
            atomicAdd(&hist[(uint32_t)c.y >> CSH], 1u);
            atomicAdd(&hist[(uint32_t)c.z >> CSH], 1u);
            atomicAdd(&hist[(uint32_t)c.w >> CSH], 1u);
            rec[it * 4 + 0] = ((uint32_t)c.x << 6) | (uint32_t)xc[r.x];
            rec[it * 4 + 1] = ((uint32_t)c.y << 6) | (uint32_t)xc[r.y];
            rec[it * 4 + 2] = ((uint32_t)c.z << 6) | (uint32_t)xc[r.z];
            rec[it * 4 + 3] = ((uint32_t)c.w << 6) | (uint32_t)xc[r.w];
        }
    } else {
        int n4 = nend >> 2;
        for (int k = t; k < n4; k += 256) {
            int4 c = col4[k];
            atomicAdd(&hist[(uint32_t)c.x >> CSH], 1u);
            atomicAdd(&hist[(uint32_t)c.y >> CSH], 1u);
            atomicAdd(&hist[(uint32_t)c.z >> CSH], 1u);
            atomicAdd(&hist[(uint32_t)c.w >> CSH], 1u);
        }
        for (int k = (n4 << 2) + t; k < nend; k += 256)
            atomicAdd(&hist[(uint32_t)col[base + k] >> CSH], 1u);
    }
    __syncthreads();

    // scan (thread t owns buckets 2t,2t+1), reserve global runs, pack state
    int b0 = 2 * t;
    uint32_t h0 = hist[b0], h1 = hist[b0 + 1];
    uint32_t s = h0 + h1;
    uint32_t inc = s;
    for (int off = 1; off < 64; off <<= 1) {
        uint32_t nv = __shfl_up(inc, (unsigned)off, 64);
        if (lane >= off) inc += nv;
    }
    if (lane == 63) wsum[wid] = inc;
    __syncthreads();
    uint32_t woff = 0;
    for (int w = 0; w < wid; w++) woff += wsum[w];
    uint32_t e0 = woff + inc - s;
    uint32_t g0 = h0 ? atomicAdd(&cursor[b0], h0) : 0u;
    uint32_t g1 = h1 ? atomicAdd(&cursor[b0 + 1], h1) : 0u;
    gb16[b0] = (uint16_t)g0;
    gb16[b0 + 1] = (uint16_t)g1;
    hist[b0] = e0 << 16;
    hist[b0 + 1] = (e0 + h0) << 16;
    __syncthreads();

    // pass 2: scatter into LDS staging
    if (fast) {
#pragma unroll
        for (int it = 0; it < ITERS * 4; ++it) {
            uint32_t rv = rec[it];
            uint32_t b = rv >> 16;
            uint32_t o = atomicAdd(&hist[b], 1u);
            stage[(o >> 16) + (o & 0xFFFFu)] = (uint16_t)rv;
        }
    } else {
        int n4 = nend >> 2;
        for (int k = t; k < n4; k += 256) {
            int4 c = col4[k];
            int4 r = row4[k];
            {
                uint32_t d = (uint32_t)c.x, b = d >> CSH;
                uint32_t o = atomicAdd(&hist[b], 1u);
                stage[(o >> 16) + (o & 0xFFFFu)] = (uint16_t)(((d & 1023u) << 6) | (uint32_t)xc[r.x]);
            }
            {
                uint32_t d = (uint32_t)c.y, b = d >> CSH;
                uint32_t o = atomicAdd(&hist[b], 1u);
                stage[(o >> 16) + (o & 0xFFFFu)] = (uint16_t)(((d & 1023u) << 6) | (uint32_t)xc[r.y]);
            }
            {
                uint32_t d = (uint32_t)c.z, b = d >> CSH;
                uint32_t o = atomicAdd(&hist[b], 1u);
                stage[(o >> 16) + (o & 0xFFFFu)] = (uint16_t)(((d & 1023u) << 6) | (uint32_t)xc[r.z]);
            }
            {
                uint32_t d = (uint32_t)c.w, b = d >> CSH;
                uint32_t o = atomicAdd(&hist[b], 1u);
                stage[(o >> 16) + (o & 0xFFFFu)] = (uint16_t)(((d & 1023u) << 6) | (uint32_t)xc[r.w]);
            }
        }
        for (int k = (n4 << 2) + t; k < nend; k += 256) {
            int i = base + k;
            uint32_t d = (uint32_t)col[i], b = d >> CSH;
            uint32_t o = atomicAdd(&hist[b], 1u);
            stage[(o >> 16) + (o & 0xFFFFu)] = (uint16_t)(((d & 1023u) << 6) | (uint32_t)xc[row[i]]);
        }
    }
    __syncthreads();

    // pass 3: burst copy-out; 16 lanes per bucket (runs avg ~32 records)
    int sub = lane >> 4, l16 = lane & 15;
    for (int b = wid * 4 + sub; b < NBKT; b += 16) {
        uint32_t hv = hist[b];
        uint32_t cnt = hv & 0xFFFFu;
        if (!cnt) continue;
        uint32_t s0 = hv >> 16;
        uint16_t* dst = bins + (size_t)b * (uint32_t)cap + gb16[b];
        for (uint32_t off = l16; off < cnt; off += 16)
            dst[off] = stage[s0 + off];
    }
}

// ---- P2: direct per-node sum accumulation (byte-identical to R4) ----
__global__ __launch_bounds__(1024) void k_accsig(const uint16_t* __restrict__ bins,
                                                 const uint32_t* __restrict__ cursor,
                                                 const uint8_t* __restrict__ xc,
                                                 ull* __restrict__ sigs,
                                                 uint32_t* __restrict__ bcnt, int N, int cap) {
    __shared__ uint32_t sA[FINE_NODES];   // 4 KB
    __shared__ uint32_t sB[FINE_NODES];   // 4 KB
    __shared__ uint32_t lA[64], lB[64];   // 512 B LUT copies (LDS-resident)
    int t = threadIdx.x;
    int b = blockIdx.x;
    sA[t] = 0;
    sB[t] = 0;
    if (t < 64) { lA[t] = LUT.ha[t]; lB[t] = LUT.hb[t]; }
    __syncthreads();

    uint32_t m = cursor[b];
    const uint16_t* mybins = bins + (size_t)b * (uint32_t)cap;
    const uint2* p16v = (const uint2*)mybins;   // cap % 4 == 0 -> 8B aligned
    uint32_t m4 = m >> 2;
    for (uint32_t k = t; k < m4; k += 1024) {
        uint2 rv = p16v[k];
        {
            uint32_t rec = rv.x & 0xFFFFu, n = rec >> 6, c = rec & 63u;
            atomicAdd(&sA[n], lA[c]);
            atomicAdd(&sB[n], lB[c]);
        }
        {
            uint32_t rec = rv.x >> 16, n = rec >> 6, c = rec & 63u;
            atomicAdd(&sA[n], lA[c]);
            atomicAdd(&sB[n], lB[c]);
        }
        {
            uint32_t rec = rv.y & 0xFFFFu, n = rec >> 6, c = rec & 63u;
            atomicAdd(&sA[n], lA[c]);
            atomicAdd(&sB[n], lB[c]);
        }
        {
            uint32_t rec = rv.y >> 16, n = rec >> 6, c = rec & 63u;
            atomicAdd(&sA[n], lA[c]);
            atomicAdd(&sB[n], lB[c]);
        }
    }
    for (uint32_t k = (m4 << 2) + t; k < m; k += 1024) {
        uint32_t rec = mybins[k], n = rec >> 6, c = rec & 63u;
        atomicAdd(&sA[n], lA[c]);
        atomicAdd(&sB[n], lB[c]);
    }
    __syncthreads();

    int g = b * FINE_NODES + t;
    if (g < N) {
        uint32_t xv = (uint32_t)xc[g];
        uint32_t ha = lA[xv];
        uint32_t hb = lB[xv];
        uint32_t sa = mixh(ha * 0x27D4EB2Fu + sA[t], 0xC2B2AE3Du, 0x165667B1u);
        uint32_t sb = mixh(hb * 0x61C88647u + sB[t], 0x045D9F3Bu, 0x27D4EB2Fu);
        ull key = ((ull)sa << 32) | (ull)sb;
        sigs[g] = key;
        atomicAdd(&bcnt[(uint32_t)(key >> (64 - LOG_B))], 1u);
    }
}

// ---- exclusive scan: shfl wave-scan, thread owns 4 elements, uint4 I/O ----
__global__ __launch_bounds__(256) void k_scan1(const uint32_t* __restrict__ in,
                                               uint32_t* __restrict__ out,
                                               uint32_t* __restrict__ part) {
    __shared__ uint32_t wsum[4];
    int t = threadIdx.x;
    int lane = t & 63, wid = t >> 6;
    int base = blockIdx.x * 1024 + 4 * t;
    uint4 v = *(const uint4*)(in + base);
    uint32_t s = v.x + v.y + v.z + v.w;
    uint32_t inc = s;
    for (int off = 1; off < 64; off <<= 1) {
        uint32_t nv = __shfl_up(inc, (unsigned)off, 64);
        if (lane >= off) inc += nv;
    }
    if (lane == 63) wsum[wid] = inc;
    __syncthreads();
    uint32_t woff = 0;
    for (int w = 0; w < wid; w++) woff += wsum[w];
    uint32_t e = woff + inc - s;
    uint4 o;
    o.x = e; o.y = e + v.x; o.z = o.y + v.y; o.w = o.z + v.z;
    *(uint4*)(out + base) = o;
    if (t == 255) part[blockIdx.x] = wsum[0] + wsum[1] + wsum[2] + wsum[3];
}

__global__ void k_scan2(uint32_t* __restrict__ part) {  // 256 entries (zero-padded)
    __shared__ uint32_t s[256];
    int t = threadIdx.x;
    uint32_t v = part[t];
    s[t] = v;
    __syncthreads();
    for (int off = 1; off < 256; off <<= 1) {
        uint32_t add = (t >= off) ? s[t - off] : 0u;
        __syncthreads();
        s[t] += add;
        __syncthreads();
    }
    part[t] = s[t] - v;                  // exclusive
}

__global__ __launch_bounds__(256) void k_scan3(uint32_t* __restrict__ out,
                                               const uint32_t* __restrict__ part) {
    int base = blockIdx.x * 1024 + 4 * threadIdx.x;
    uint32_t p = part[blockIdx.x];
    uint4 v = *(const uint4*)(out + base);
    v.x += p; v.y += p; v.z += p; v.w += p;
    *(uint4*)(out + base) = v;
}

// ---- scatter keys into sort buckets. boff doubles as the cursor:
// pos = atomicAdd(&boff[b],1) -- one random op/node instead of two
// (deletes the bcur array + its dependent read). After this kernel
// boff[b] == end of bucket b == start of bucket b+1. ----
__global__ void k_scatter(const ull* __restrict__ sigs,
                          uint32_t* __restrict__ boff,
                          ull* __restrict__ skey, uint32_t* __restrict__ snode,
                          int N) {
    int i = blockIdx.x * blockDim.x + threadIdx.x;
    if (i >= N) return;
    ull key = sigs[i];
    uint32_t b = (uint32_t)(key >> (64 - LOG_B));
    uint32_t pos = atomicAdd(&boff[b], 1u);
    skey[pos] = key;
    snode[pos] = (uint32_t)i;
}

// ---- per-bucket insertion sort, distinct counts.
// Post-scatter boff[b] = end of bucket b, so range = [b?boff[b-1]:0, boff[b]). ----
__global__ void k_bsort(ull* __restrict__ skey, uint32_t* __restrict__ snode,
                        const uint32_t* __restrict__ boff, uint32_t* __restrict__ ldx,
                        uint32_t* __restrict__ dcnt, int N) {
    int b = blockIdx.x * blockDim.x + threadIdx.x;
    if (b >= (int)NB) return;
    uint32_t s0 = b ? boff[b - 1] : 0u;
    uint32_t s1 = boff[b];
    for (uint32_t i = s0 + 1; i < s1; i++) {
        ull k = skey[i];
        uint32_t nd = snode[i];
        uint32_t j = i;
        while (j > s0 && skey[j - 1] > k) {
            skey[j] = skey[j - 1];
            snode[j] = snode[j - 1];
            j--;
        }
        skey[j] = k;
        snode[j] = nd;
    }
    uint32_t d = 0;
    ull prev = 0ull;
    for (uint32_t i = s0; i < s1; i++) {
        ull k = skey[i];
        if (i == s0 || k != prev) d++;
        prev = k;
        ldx[i] = d - 1;
    }
    dcnt[b] = d;
}

// ---- final label write ----
__global__ void k_out(const ull* __restrict__ skey,
                      const uint32_t* __restrict__ snode, const uint32_t* __restrict__ ldx,
                      const uint32_t* __restrict__ doff, int* __restrict__ out, int N) {
    int i = blockIdx.x * blockDim.x + threadIdx.x;
    if (i >= N) return;
    ull key = skey[i];
    uint32_t b = (uint32_t)(key >> (64 - LOG_B));
    out[snode[i]] = (int)(doff[b] + ldx[i]);
}

extern "C" void kernel_launch(void* const* d_in, const int* in_sizes, int n_in,
                              void* d_out, int out_size, void* d_ws, size_t ws_size,
                              hipStream_t stream) {
    const int* x = (const int*)d_in[0];
    const int* ei = (const int*)d_in[1];
    int N = in_sizes[0];
    int E = in_sizes[1] / 2;
    const int* row = ei;
    const int* col = ei + E;

    int nacc = (N + FINE_NODES - 1) / FINE_NODES;        // 489
    int cap = E / NBKT + (E / NBKT) / 16 + 1024;         // mean + margin (<65536)
    cap = (cap + 3) & ~3;                                // 8B-aligned runs for uint2 loads

    char* p = (char*)d_ws;
    auto alloc = [&](size_t bytes) -> char* {
        char* r = p;
        p += (bytes + 255) & ~(size_t)255;
        return r;
    };
    // zero-needing region first (single memsetAsync)
    uint32_t* cursor = (uint32_t*)alloc((size_t)NBKT * 4);
    uint32_t* bcnt   = (uint32_t*)alloc((size_t)NB * 4);
    uint32_t* dcnt   = (uint32_t*)alloc((size_t)NB * 4);
    uint32_t* part   = (uint32_t*)alloc(256 * 4);
    size_t zbytes = (size_t)(p - (char*)d_ws);
    uint8_t* xc = (uint8_t*)alloc((size_t)N);
    ull* sigs = (ull*)alloc((size_t)N * 8);
    uint16_t* bins = (uint16_t*)alloc((size_t)NBKT * cap * 2);
    // post-accsig aliases inside the (then-dead) bins region:
    char* q = (char*)bins;
    auto alias = [&](size_t bytes) -> char* {
        char* r = q;
        q += (bytes + 255) & ~(size_t)255;
        return r;
    };
    ull* skey       = (ull*)alias((size_t)N * 8);
    uint32_t* snode = (uint32_t*)alias((size_t)N * 4);
    uint32_t* ldx   = (uint32_t*)alias((size_t)N * 4);
    uint32_t* boff  = (uint32_t*)alias((size_t)NB * 4);
    uint32_t* doff  = (uint32_t*)alias((size_t)NB * 4);

    hipMemsetAsync(d_ws, 0, zbytes, stream);

    int nbN = (N + 255) / 256;
    int nbBin = (E + EPB - 1) / EPB;
    int n4 = N / 4;                       // N = 500k, divisible by 4

    k_pre<<<(n4 + 255) / 256, 256, 0, stream>>>((const int4*)x, (uchar4*)xc, n4);
    k_bin<<<nbBin, 256, 0, stream>>>(row, col, xc, bins, cursor, E, cap);
    k_accsig<<<nacc, 1024, 0, stream>>>(bins, cursor, xc, sigs, bcnt, N, cap);

    k_scan1<<<NB / 1024, 256, 0, stream>>>(bcnt, boff, part);
    k_scan2<<<1, 256, 0, stream>>>(part);
    k_scan3<<<NB / 1024, 256, 0, stream>>>(boff, part);

    k_scatter<<<nbN, 256, 0, stream>>>(sigs, boff, skey, snode, N);
    k_bsort<<<NB / 256, 256, 0, stream>>>(skey, snode, boff, ldx, dcnt, N);

    k_scan1<<<NB / 1024, 256, 0, stream>>>(dcnt, doff, part);
    k_scan2<<<1, 256, 0, stream>>>(part);
    k_scan3<<<NB / 1024, 256, 0, stream>>>(doff, part);

    k_out<<<nbN, 256, 0, stream>>>(skey, snode, ldx, doff, (int*)d_out, N);
}